// Round 3
// baseline (517.420 us; speedup 1.0000x reference)
//
#include <hip/hip_runtime.h>
#include <cstdint>
#include <cstddef>

// ---------------- problem constants ----------------
#define BATCH 16
#define NBOX 25200
#define NCH 85          // 4 box + 1 obj + 80 cls
#define KPRE 1024
#define MAXDET 1000
#define NCAND_MAX 4096
#define HIST_SIZE 16384 // histogram over (key >> 18)

__device__ __forceinline__ unsigned key_of(float s) {
    // monotone map: larger score -> SMALLER key (ascending sort = descending score)
    unsigned u = __float_as_uint(s);
    unsigned m = (u & 0x80000000u) ? ~u : (u | 0x80000000u);
    return ~m;
}

// ---------------- kernel 1: per-box score/argmax, key + histogram ----------------
// 256-thread block handles 256 boxes in 2 phases of 128 rows staged in LDS.
// 2 threads per box, 40 classes each, shfl_xor combine. Valid boxes only -> hist.
__global__ __launch_bounds__(256) void score_kernel(const float* __restrict__ x,
                                                    unsigned* __restrict__ k32,
                                                    unsigned char* __restrict__ cls8,
                                                    unsigned* __restrict__ hist) {
    __shared__ float lds[128 * NCH];            // 43520 B
    int t = threadIdx.x;
    int box0 = blockIdx.x * 256;

    for (int phase = 0; phase < 2; phase++) {
        int r0 = box0 + phase * 128;
        const float4* src = (const float4*)(x + (size_t)r0 * NCH);
        float4* dst = (float4*)lds;
        for (int idx = t; idx < (128 * NCH) / 4; idx += 256)
            dst[idx] = src[idx];
        __syncthreads();

        int box = t >> 1;                       // 0..127
        int half = t & 1;
        const float* row = lds + box * NCH;
        float obj = row[4];
        int cbase = 5 + half * 40;
        float v = -1e30f; int c = 0;
        #pragma unroll 8
        for (int j = 0; j < 40; j++) {
            float s = row[cbase + j] * obj;
            if (s > v) { v = s; c = half * 40 + j; }   // strict > keeps first occurrence
        }
        // combine halves; tie -> lower class index (half0)
        float ov = __shfl_xor(v, 1);
        int oc = __shfl_xor(c, 1);
        if (half == 0) { if (ov > v)  { v = ov; c = oc; } }
        else           { if (ov >= v) { v = ov; c = oc; } }

        if (half == 0) {
            int wid = r0 + box;
            bool validb = (obj > 0.25f) && (v > 0.25f);
            float score = validb ? v : -1.0f;
            unsigned k = key_of(score);
            k32[wid] = k;
            cls8[wid] = (unsigned char)c;
            if (validb) {                        // invalid boxes never join the top-k race
                int b = wid / NBOX;
                atomicAdd(&hist[b * HIST_SIZE + (k >> 18)], 1u);
            }
        }
        __syncthreads();                         // protect LDS before next phase restage
    }
}

// ---------------- kernel 2: find histogram cutoff prefix covering rank KPRE ----------------
__global__ __launch_bounds__(256) void select_cutoff(const unsigned* __restrict__ hist,
                                                     unsigned* __restrict__ cutoff) {
    int b = blockIdx.x, t = threadIdx.x;
    __shared__ unsigned part[256];
    const unsigned* h = hist + (size_t)b * HIST_SIZE;
    unsigned s = 0;
    for (int j = 0; j < HIST_SIZE / 256; j++) s += h[t * (HIST_SIZE / 256) + j];
    part[t] = s;
    __syncthreads();
    if (t == 0) {
        unsigned cum = 0;
        int chunk = 0;
        for (; chunk < 256; chunk++) {
            if (cum + part[chunk] >= KPRE) break;
            cum += part[chunk];
        }
        unsigned P = HIST_SIZE - 1;             // fewer than KPRE valid -> take all valid
        if (chunk < 256) {
            int base = chunk * (HIST_SIZE / 256);
            for (int j = 0; j < HIST_SIZE / 256; j++) {
                cum += h[base + j];
                if (cum >= KPRE) { P = base + j; break; }
            }
        }
        cutoff[b] = P;
    }
}

// ---------------- kernel 3: compact valid candidates (key64 = k32<<32 | idx) ----------------
// 2D grid: blockIdx.y = batch (wave-uniform), wave-aggregated ncand atomic.
__global__ __launch_bounds__(256) void compact_kernel(const unsigned* __restrict__ k32,
                                                      const unsigned* __restrict__ cutoff,
                                                      unsigned* __restrict__ ncand,
                                                      unsigned long long* __restrict__ cand) {
    int b = blockIdx.y;
    int i = blockIdx.x * 256 + threadIdx.x;
    bool pass = false;
    unsigned k = 0;
    if (i < NBOX) {
        k = k32[(size_t)b * NBOX + i];
        pass = ((int)k >= 0) && ((k >> 18) <= cutoff[b]);   // sign bit set = invalid (-1 score)
    }
    unsigned long long m = __ballot(pass);
    if (!m) return;
    int lane = threadIdx.x & 63;
    int rank = __popcll(lane ? (m & ((~0ull) >> (64 - lane))) : 0ull);
    int leader = (int)(__ffsll((unsigned long long)m) - 1);
    unsigned base = 0;
    if (lane == leader) base = atomicAdd(&ncand[b], (unsigned)__popcll(m));
    base = __shfl(base, leader);
    if (pass) {
        unsigned pos = base + (unsigned)rank;
        if (pos < NCAND_MAX)
            cand[(size_t)b * NCAND_MAX + pos] = ((unsigned long long)k << 32) | (unsigned)i;
    }
}

// ---------------- kernel 4: bitonic sort candidates, gather top-1024 ----------------
__global__ __launch_bounds__(1024) void sort_gather(const unsigned long long* __restrict__ cand,
                                                    const unsigned* __restrict__ ncand,
                                                    const float* __restrict__ x,
                                                    const unsigned char* __restrict__ cls8,
                                                    float4* __restrict__ topbox,
                                                    float4* __restrict__ topoff,
                                                    float* __restrict__ topconf,
                                                    float* __restrict__ topcls) {
#pragma clang fp contract(off)
    __shared__ unsigned long long keys[NCAND_MAX];
    int b = blockIdx.x, t = threadIdx.x;
    int n = (int)ncand[b];
    if (n > NCAND_MAX) n = NCAND_MAX;
    for (int q = 0; q < 4; q++) {
        int s = t + q * 1024;
        keys[s] = (s < n) ? cand[(size_t)b * NCAND_MAX + s] : ~0ull;
    }
    __syncthreads();
    // ascending bitonic sort: key ascending = score descending, ties by ascending idx
    for (int k = 2; k <= NCAND_MAX; k <<= 1) {
        for (int j = k >> 1; j > 0; j >>= 1) {
            for (int q = 0; q < 4; q++) {
                int i = t + q * 1024;
                int ixj = i ^ j;
                if (ixj > i) {
                    unsigned long long a = keys[i], bb = keys[ixj];
                    bool up = ((i & k) == 0);
                    if ((a > bb) == up) { keys[i] = bb; keys[ixj] = a; }
                }
            }
            __syncthreads();
        }
    }
    // gather rank t (t in [0,1024))
    float conf; float4 box; float clsf;
    if (t < n) {
        unsigned long long key = keys[t];
        unsigned kk = (unsigned)(key >> 32);
        unsigned idx = (unsigned)(key & 0xFFFFFFFFu);
        unsigned m = ~kk;
        unsigned bits = (m & 0x80000000u) ? (m & 0x7FFFFFFFu) : ~m;
        conf = __uint_as_float(bits);           // exact original score
        size_t base = ((size_t)b * NBOX + idx) * NCH;
        float cx = x[base + 0], cy = x[base + 1], w = x[base + 2], h = x[base + 3];
        box = make_float4(cx - w * 0.5f, cy - h * 0.5f, cx + w * 0.5f, cy + h * 0.5f);
        clsf = (float)cls8[(size_t)b * NBOX + idx];
    } else {
        conf = -1.0f; box = make_float4(0.f, 0.f, 0.f, 0.f); clsf = 0.f;
    }
    int o = (b << 10) + t;
    topconf[o] = conf;
    topcls[o] = clsf;
    topbox[o] = box;
    float off = clsf * 4096.0f;
    topoff[o] = make_float4(box.x + off, box.y + off, box.z + off, box.w + off);
}

// ---------------- kernel 5: pairwise IoU suppression bitmask ----------------
// grid: BATCH*64 blocks of 256; block handles 16 i-rows x 16 j-words of one batch
__global__ __launch_bounds__(256) void iou_mask(const float4* __restrict__ topoff,
                                                unsigned long long* __restrict__ mask) {
#pragma clang fp contract(off)
    __shared__ float4 soff[KPRE];
    int b = blockIdx.x >> 6;
    int blk = blockIdx.x & 63;
    int t = threadIdx.x;
    for (int q = 0; q < 4; q++) {
        int s = t + q * 256;
        soff[s] = topoff[(b << 10) + s];
    }
    __syncthreads();
    int i = (blk << 4) + (t >> 4);
    int w = t & 15;
    float4 a = soff[i];
    float area_a = (a.z - a.x) * (a.w - a.y);
    unsigned long long bits = 0;
    int jbase = w << 6;
    for (int jj = 0; jj < 64; jj++) {
        int j = jbase + jj;
        float4 bb = soff[j];
        float area_b = (bb.z - bb.x) * (bb.w - bb.y);
        float ltx = fmaxf(a.x, bb.x), lty = fmaxf(a.y, bb.y);
        float rbx = fminf(a.z, bb.z), rby = fminf(a.w, bb.w);
        float wx = fmaxf(rbx - ltx, 0.0f), wy = fmaxf(rby - lty, 0.0f);
        float inter = wx * wy;
        float iou = inter / (area_a + area_b - inter + 1e-7f);
        if (j > i && iou > 0.45f) bits |= (1ull << jj);
    }
    mask[((size_t)((b << 10) + i) << 4) + w] = bits;
}

// ---------------- kernel 6: greedy suppression, tiled ffs-scan (1 wave / batch) ----------------
// Cost scales with #kept boxes, not KPRE. All per-word state is wave-uniform and
// redundantly held in registers in every lane (statically indexed, fully unrolled).
__global__ __launch_bounds__(64) void nms_reduce(const unsigned long long* __restrict__ mask,
                                                 const float* __restrict__ topconf,
                                                 unsigned long long* __restrict__ keepbits) {
    int b = blockIdx.x, lane = threadIdx.x;
    const unsigned long long* mrow = mask + ((size_t)b << 14);   // 1024 rows x 16 words

    // keep0 words (wave-uniform via ballot), redundant in all lanes
    unsigned long long keep0[16];
    #pragma unroll
    for (int c = 0; c < 16; c++) {
        float cf = topconf[(b << 10) + (c << 6) + lane];
        keep0[c] = __ballot(cf > 0.0f);
    }

    // prefetch all 16 tile-diagonal words: lane l holds row (64t+l)'s word t
    unsigned long long diag[16];
    #pragma unroll
    for (int t = 0; t < 16; t++)
        diag[t] = mrow[((size_t)((t << 6) + lane) << 4) + t];

    unsigned long long remv[16];
    #pragma unroll
    for (int t = 0; t < 16; t++) remv[t] = 0;

    #pragma unroll
    for (int t = 0; t < 16; t++) {
        // ---- within-tile greedy scan over live bits only ----
        unsigned long long live = keep0[t] & ~remv[t];
        unsigned long long kept = 0;
        while (live) {
            int j = (int)__ffsll(live) - 1;          // lowest live index = next greedy keeper
            kept |= 1ull << j;
            unsigned long long dj = __shfl(diag[t], j);  // row j's within-tile suppression bits (all > j)
            live &= live - 1;                        // clear bit j
            live &= ~dj;                             // suppress within-tile victims
        }
        if (lane == 0) keepbits[b * 16 + t] = kept;

        // ---- cross-tile: OR kept rows' mask words into remv (batched broadcast loads) ----
        if (t < 15) {
            unsigned long long km = kept;
            while (km) {
                int idx[8]; unsigned long long tmp = km;
                #pragma unroll
                for (int q = 0; q < 8; q++) {
                    idx[q] = tmp ? (int)__ffsll(tmp) - 1 : -1;
                    if (tmp) tmp &= tmp - 1;
                }
                km = tmp;
                #pragma unroll
                for (int q = 0; q < 8; q++) {
                    if (idx[q] >= 0) {               // wave-uniform branch
                        const ulonglong2* rp =
                            (const ulonglong2*)(mrow + ((size_t)((t << 6) + idx[q]) << 4));
                        #pragma unroll
                        for (int h = 0; h < 8; h++) {
                            ulonglong2 v = rp[h];    // broadcast load (same addr all lanes)
                            remv[2 * h] |= v.x;
                            remv[2 * h + 1] |= v.y;
                        }
                    }
                }
            }
        }
    }
}

// ---------------- kernel 7: ordered compaction of kept entries -> dets + vmask ----------------
__global__ __launch_bounds__(1024) void finalize_kernel(const unsigned long long* __restrict__ keepbits,
                                                        const float4* __restrict__ topbox,
                                                        const float* __restrict__ topconf,
                                                        const float* __restrict__ topcls,
                                                        float* __restrict__ dets,
                                                        float* __restrict__ vmask) {
    int b = blockIdx.x, r = threadIdx.x;
    int w = r >> 6, l = r & 63;
    unsigned long long word = keepbits[b * 16 + w];
    int keep = (int)((word >> l) & 1ull);
    __shared__ int wsum[16];
    if (l == 0) wsum[w] = __popcll(word);
    __syncthreads();
    int base = 0, total = 0;
    for (int q = 0; q < 16; q++) {
        int c = wsum[q];
        total += c;
        if (q < w) base += c;
    }
    int rank = base + __popcll((l == 0) ? 0ull : (word & ((~0ull) >> (64 - l))));
    float* drow = dets + (size_t)b * (MAXDET * 6);
    float* vm = vmask + (size_t)b * MAXDET;
    if (r < MAXDET && r >= total) {
#pragma unroll
        for (int cc = 0; cc < 6; cc++) drow[r * 6 + cc] = 0.0f;
        vm[r] = 0.0f;
    }
    if (keep && rank < MAXDET) {
        int o = (b << 10) + r;
        float4 bx = topbox[o];
        drow[rank * 6 + 0] = bx.x;
        drow[rank * 6 + 1] = bx.y;
        drow[rank * 6 + 2] = bx.z;
        drow[rank * 6 + 3] = bx.w;
        drow[rank * 6 + 4] = topconf[o];
        drow[rank * 6 + 5] = topcls[o];
        vm[rank] = 1.0f;
    }
}

// ---------------- launcher ----------------
extern "C" void kernel_launch(void* const* d_in, const int* in_sizes, int n_in,
                              void* d_out, int out_size, void* d_ws, size_t ws_size,
                              hipStream_t stream) {
    const float* x = (const float*)d_in[0];
    char* w = (char*)d_ws;

    // workspace layout (bytes), total ~6.35 MB
    unsigned long long* cand     = (unsigned long long*)(w + 0);        // 16*4096*8 = 524288
    unsigned long long* mask     = (unsigned long long*)(w + 524288);   // 16*1024*16*8 = 2097152
    unsigned long long* keepbits = (unsigned long long*)(w + 2621440);  // 16*16*8 = 2048
    unsigned*           hist     = (unsigned*)(w + 2623488);            // 16*16384*4 = 1048576
    unsigned*           k32      = (unsigned*)(w + 3672064);            // 403200*4 = 1612800
    float4*             topbox   = (float4*)(w + 5284864);              // 16*1024*16 = 262144
    float4*             topoff   = (float4*)(w + 5547008);              // 262144
    float*              topconf  = (float*)(w + 5809152);               // 65536
    float*              topcls   = (float*)(w + 5874688);               // 65536
    unsigned*           cutoff   = (unsigned*)(w + 5940224);            // 64
    unsigned*           ncand    = (unsigned*)(w + 5940288);            // 64
    unsigned char*      cls8     = (unsigned char*)(w + 5940352);       // 403200
    if (ws_size < 6343552) return;  // insufficient scratch -> deterministic failure

    hipMemsetAsync(hist, 0, (size_t)BATCH * HIST_SIZE * sizeof(unsigned), stream);
    hipMemsetAsync(ncand, 0, (size_t)BATCH * sizeof(unsigned), stream);

    score_kernel<<<(BATCH * NBOX) / 256, 256, 0, stream>>>(x, k32, cls8, hist);
    select_cutoff<<<BATCH, 256, 0, stream>>>(hist, cutoff);
    compact_kernel<<<dim3((NBOX + 255) / 256, BATCH), 256, 0, stream>>>(k32, cutoff, ncand, cand);
    sort_gather<<<BATCH, 1024, 0, stream>>>(cand, ncand, x, cls8, topbox, topoff, topconf, topcls);
    iou_mask<<<BATCH * 64, 256, 0, stream>>>(topoff, mask);
    nms_reduce<<<BATCH, 64, 0, stream>>>(mask, topconf, keepbits);

    float* dets = (float*)d_out;
    float* vmask = dets + (size_t)BATCH * MAXDET * 6;
    finalize_kernel<<<BATCH, 1024, 0, stream>>>(keepbits, topbox, topconf, topcls, dets, vmask);
}

// Round 4
// 261.202 us; speedup vs baseline: 1.9809x; 1.9809x over previous
//
#include <hip/hip_runtime.h>
#include <cstdint>
#include <cstddef>

// ---------------- problem constants ----------------
#define BATCH 16
#define NBOX 25200
#define NCH 85          // 4 box + 1 obj + 80 cls
#define KPRE 1024
#define MAXDET 1000
#define NCAND_MAX 4096
#define HIST_SIZE 16384 // histogram over (key >> 18)

__device__ __forceinline__ unsigned key_of(float s) {
    // monotone map: larger score -> SMALLER key (ascending sort = descending score)
    unsigned u = __float_as_uint(s);
    unsigned m = (u & 0x80000000u) ? ~u : (u | 0x80000000u);
    return ~m;
}

// ---------------- kernel 1: per-box score/argmax, key + histogram ----------------
// 256-thread block handles 256 boxes in 2 phases of 128 rows staged in LDS.
__global__ __launch_bounds__(256) void score_kernel(const float* __restrict__ x,
                                                    unsigned* __restrict__ k32,
                                                    unsigned char* __restrict__ cls8,
                                                    unsigned* __restrict__ hist) {
    __shared__ float lds[128 * NCH];            // 43520 B
    int t = threadIdx.x;
    int box0 = blockIdx.x * 256;

    for (int phase = 0; phase < 2; phase++) {
        int r0 = box0 + phase * 128;
        const float4* src = (const float4*)(x + (size_t)r0 * NCH);
        float4* dst = (float4*)lds;
        for (int idx = t; idx < (128 * NCH) / 4; idx += 256)
            dst[idx] = src[idx];
        __syncthreads();

        int box = t >> 1;                       // 0..127
        int half = t & 1;
        const float* row = lds + box * NCH;
        float obj = row[4];
        int cbase = 5 + half * 40;
        float v = -1e30f; int c = 0;
        #pragma unroll 8
        for (int j = 0; j < 40; j++) {
            float s = row[cbase + j] * obj;
            if (s > v) { v = s; c = half * 40 + j; }   // strict > keeps first occurrence
        }
        // combine halves; tie -> lower class index (half0)
        float ov = __shfl_xor(v, 1);
        int oc = __shfl_xor(c, 1);
        if (half == 0) { if (ov > v)  { v = ov; c = oc; } }
        else           { if (ov >= v) { v = ov; c = oc; } }

        if (half == 0) {
            int wid = r0 + box;
            bool validb = (obj > 0.25f) && (v > 0.25f);
            float score = validb ? v : -1.0f;
            unsigned k = key_of(score);
            k32[wid] = k;
            cls8[wid] = (unsigned char)c;
            if (validb) {                        // invalid boxes never join the top-k race
                int b = wid / NBOX;
                atomicAdd(&hist[b * HIST_SIZE + (k >> 18)], 1u);
            }
        }
        __syncthreads();                         // protect LDS before next phase restage
    }
}

// ---------------- kernel 2: find histogram cutoff prefix covering rank KPRE ----------------
__global__ __launch_bounds__(256) void select_cutoff(const unsigned* __restrict__ hist,
                                                     unsigned* __restrict__ cutoff) {
    int b = blockIdx.x, t = threadIdx.x;
    __shared__ unsigned part[256];
    const unsigned* h = hist + (size_t)b * HIST_SIZE;
    unsigned s = 0;
    for (int j = 0; j < HIST_SIZE / 256; j++) s += h[t * (HIST_SIZE / 256) + j];
    part[t] = s;
    __syncthreads();
    if (t == 0) {
        unsigned cum = 0;
        int chunk = 0;
        for (; chunk < 256; chunk++) {
            if (cum + part[chunk] >= KPRE) break;
            cum += part[chunk];
        }
        unsigned P = HIST_SIZE - 1;             // fewer than KPRE valid -> take all valid
        if (chunk < 256) {
            int base = chunk * (HIST_SIZE / 256);
            for (int j = 0; j < HIST_SIZE / 256; j++) {
                cum += h[base + j];
                if (cum >= KPRE) { P = base + j; break; }
            }
        }
        cutoff[b] = P;
    }
}

// ---------------- kernel 3: compact valid candidates (key64 = k32<<32 | idx) ----------------
__global__ __launch_bounds__(256) void compact_kernel(const unsigned* __restrict__ k32,
                                                      const unsigned* __restrict__ cutoff,
                                                      unsigned* __restrict__ ncand,
                                                      unsigned long long* __restrict__ cand) {
    int b = blockIdx.y;
    int i = blockIdx.x * 256 + threadIdx.x;
    bool pass = false;
    unsigned k = 0;
    if (i < NBOX) {
        k = k32[(size_t)b * NBOX + i];
        pass = ((int)k >= 0) && ((k >> 18) <= cutoff[b]);   // sign bit set = invalid (-1 score)
    }
    unsigned long long m = __ballot(pass);
    if (!m) return;
    int lane = threadIdx.x & 63;
    int rank = __popcll(lane ? (m & ((~0ull) >> (64 - lane))) : 0ull);
    int leader = (int)(__ffsll((unsigned long long)m) - 1);
    unsigned base = 0;
    if (lane == leader) base = atomicAdd(&ncand[b], (unsigned)__popcll(m));
    base = __shfl(base, leader);
    if (pass) {
        unsigned pos = base + (unsigned)rank;
        if (pos < NCAND_MAX)
            cand[(size_t)b * NCAND_MAX + pos] = ((unsigned long long)k << 32) | (unsigned)i;
    }
}

// ---------------- kernel 4: bitonic sort candidates, gather top-1024 ----------------
__global__ __launch_bounds__(1024) void sort_gather(const unsigned long long* __restrict__ cand,
                                                    const unsigned* __restrict__ ncand,
                                                    const float* __restrict__ x,
                                                    const unsigned char* __restrict__ cls8,
                                                    float4* __restrict__ topbox,
                                                    float4* __restrict__ topoff,
                                                    float* __restrict__ topconf,
                                                    float* __restrict__ topcls) {
#pragma clang fp contract(off)
    __shared__ unsigned long long keys[NCAND_MAX];
    int b = blockIdx.x, t = threadIdx.x;
    int n = (int)ncand[b];
    if (n > NCAND_MAX) n = NCAND_MAX;
    for (int q = 0; q < 4; q++) {
        int s = t + q * 1024;
        keys[s] = (s < n) ? cand[(size_t)b * NCAND_MAX + s] : ~0ull;
    }
    __syncthreads();
    // ascending bitonic sort: key ascending = score descending, ties by ascending idx
    for (int k = 2; k <= NCAND_MAX; k <<= 1) {
        for (int j = k >> 1; j > 0; j >>= 1) {
            for (int q = 0; q < 4; q++) {
                int i = t + q * 1024;
                int ixj = i ^ j;
                if (ixj > i) {
                    unsigned long long a = keys[i], bb = keys[ixj];
                    bool up = ((i & k) == 0);
                    if ((a > bb) == up) { keys[i] = bb; keys[ixj] = a; }
                }
            }
            __syncthreads();
        }
    }
    // gather rank t (t in [0,1024))
    float conf; float4 box; float clsf;
    if (t < n) {
        unsigned long long key = keys[t];
        unsigned kk = (unsigned)(key >> 32);
        unsigned idx = (unsigned)(key & 0xFFFFFFFFu);
        unsigned m = ~kk;
        unsigned bits = (m & 0x80000000u) ? (m & 0x7FFFFFFFu) : ~m;
        conf = __uint_as_float(bits);           // exact original score
        size_t base = ((size_t)b * NBOX + idx) * NCH;
        float cx = x[base + 0], cy = x[base + 1], w = x[base + 2], h = x[base + 3];
        box = make_float4(cx - w * 0.5f, cy - h * 0.5f, cx + w * 0.5f, cy + h * 0.5f);
        clsf = (float)cls8[(size_t)b * NBOX + idx];
    } else {
        conf = -1.0f; box = make_float4(0.f, 0.f, 0.f, 0.f); clsf = 0.f;
    }
    int o = (b << 10) + t;
    topconf[o] = conf;
    topcls[o] = clsf;
    topbox[o] = box;
    float off = clsf * 4096.0f;
    topoff[o] = make_float4(box.x + off, box.y + off, box.z + off, box.w + off);
}

// ---------------- kernel 5: pairwise IoU suppression bitmask + per-row summary ----------------
// grid: BATCH*64 blocks of 256; block handles 16 i-rows x 16 j-words of one batch.
// summ[row] bit w = (mask word w of row) != 0  -- lets nms_reduce skip zero words.
__global__ __launch_bounds__(256) void iou_mask(const float4* __restrict__ topoff,
                                                unsigned long long* __restrict__ mask,
                                                unsigned short* __restrict__ summ) {
#pragma clang fp contract(off)
    __shared__ float4 soff[KPRE];
    int b = blockIdx.x >> 6;
    int blk = blockIdx.x & 63;
    int t = threadIdx.x;
    for (int q = 0; q < 4; q++) {
        int s = t + q * 256;
        soff[s] = topoff[(b << 10) + s];
    }
    __syncthreads();
    int i = (blk << 4) + (t >> 4);
    int w = t & 15;
    float4 a = soff[i];
    float area_a = (a.z - a.x) * (a.w - a.y);
    unsigned long long bits = 0;
    int jbase = w << 6;
    for (int jj = 0; jj < 64; jj++) {
        int j = jbase + jj;
        float4 bb = soff[j];
        float area_b = (bb.z - bb.x) * (bb.w - bb.y);
        float ltx = fmaxf(a.x, bb.x), lty = fmaxf(a.y, bb.y);
        float rbx = fminf(a.z, bb.z), rby = fminf(a.w, bb.w);
        float wx = fmaxf(rbx - ltx, 0.0f), wy = fmaxf(rby - lty, 0.0f);
        float inter = wx * wy;
        float iou = inter / (area_a + area_b - inter + 1e-7f);
        if (j > i && iou > 0.45f) bits |= (1ull << jj);
    }
    mask[((size_t)((b << 10) + i) << 4) + w] = bits;
    // per-row 16-bit summary via wave ballot: lane l = (row quarter q=l>>4, word l&15)
    unsigned long long bal = __ballot(bits != 0ull);
    if (w == 0) {
        int l = t & 63;
        summ[(b << 10) + i] = (unsigned short)((bal >> ((l >> 4) << 4)) & 0xFFFFull);
    }
}

// ---------------- kernel 6: greedy suppression, sparsity-driven (1 wave / batch) ----------------
// Uses per-row summaries so only NONZERO mask words are ever touched.
// All per-word state wave-uniform, statically indexed (unrolled 16x16 triangle).
__global__ __launch_bounds__(64) void nms_reduce(const unsigned long long* __restrict__ mask,
                                                 const unsigned short* __restrict__ summ,
                                                 const float* __restrict__ topconf,
                                                 unsigned long long* __restrict__ keepbits) {
    int b = blockIdx.x, lane = threadIdx.x;
    const unsigned long long* mrow = mask + ((size_t)b << 14);   // 1024 rows x 16 words

    // keep0 words (wave-uniform via ballot)
    unsigned long long keep0[16];
    #pragma unroll
    for (int c = 0; c < 16; c++) {
        float cf = topconf[(b << 10) + (c << 6) + lane];
        keep0[c] = __ballot(cf > 0.0f);
    }
    // per-lane row summaries, one per tile (coalesced ushort loads)
    unsigned nz[16];
    #pragma unroll
    for (int t = 0; t < 16; t++)
        nz[t] = (unsigned)summ[(b << 10) + (t << 6) + lane];
    // prefetch all 16 tile-diagonal words (independent loads, one latency round; warms L1)
    unsigned long long diag[16];
    #pragma unroll
    for (int t = 0; t < 16; t++)
        diag[t] = mrow[((size_t)((t << 6) + lane) << 4) + t];

    unsigned long long remv[16];
    #pragma unroll
    for (int t = 0; t < 16; t++) remv[t] = 0;

    #pragma unroll
    for (int t = 0; t < 16; t++) {
        unsigned long long live = keep0[t] & ~remv[t];
        // ---- within-tile greedy: only rows flagged with in-tile suppression bits ----
        unsigned long long kept = live;
        unsigned long long pend = live & __ballot((nz[t] >> t) & 1u);
        while (pend) {
            int j = (int)__ffsll(pend) - 1;
            pend &= pend - 1;
            if ((kept >> j) & 1ull) {
                unsigned long long dj = __shfl(diag[t], j);  // bits all > j (upper-tri)
                kept &= ~dj;
                pend &= ~dj;
            }
        }
        if (lane == 0) keepbits[b * 16 + t] = kept;

        // ---- cross-tile: for each future word, load only flagged rows' words ----
        #pragma unroll
        for (int w = 0; w < 16; w++) {
            if (w > t) {
                unsigned long long wm = kept & __ballot((nz[t] >> w) & 1u);
                while (wm) {
                    int j = (int)__ffsll(wm) - 1;
                    wm &= wm - 1;
                    remv[w] |= mrow[((size_t)((t << 6) + j) << 4) + w]; // broadcast, L1-warm
                }
            }
        }
    }
}

// ---------------- kernel 7: ordered compaction of kept entries -> dets + vmask ----------------
__global__ __launch_bounds__(1024) void finalize_kernel(const unsigned long long* __restrict__ keepbits,
                                                        const float4* __restrict__ topbox,
                                                        const float* __restrict__ topconf,
                                                        const float* __restrict__ topcls,
                                                        float* __restrict__ dets,
                                                        float* __restrict__ vmask) {
    int b = blockIdx.x, r = threadIdx.x;
    int w = r >> 6, l = r & 63;
    unsigned long long word = keepbits[b * 16 + w];
    int keep = (int)((word >> l) & 1ull);
    __shared__ int wsum[16];
    if (l == 0) wsum[w] = __popcll(word);
    __syncthreads();
    int base = 0, total = 0;
    for (int q = 0; q < 16; q++) {
        int c = wsum[q];
        total += c;
        if (q < w) base += c;
    }
    int rank = base + __popcll((l == 0) ? 0ull : (word & ((~0ull) >> (64 - l))));
    float* drow = dets + (size_t)b * (MAXDET * 6);
    float* vm = vmask + (size_t)b * MAXDET;
    if (r < MAXDET && r >= total) {
#pragma unroll
        for (int cc = 0; cc < 6; cc++) drow[r * 6 + cc] = 0.0f;
        vm[r] = 0.0f;
    }
    if (keep && rank < MAXDET) {
        int o = (b << 10) + r;
        float4 bx = topbox[o];
        drow[rank * 6 + 0] = bx.x;
        drow[rank * 6 + 1] = bx.y;
        drow[rank * 6 + 2] = bx.z;
        drow[rank * 6 + 3] = bx.w;
        drow[rank * 6 + 4] = topconf[o];
        drow[rank * 6 + 5] = topcls[o];
        vm[rank] = 1.0f;
    }
}

// ---------------- launcher ----------------
extern "C" void kernel_launch(void* const* d_in, const int* in_sizes, int n_in,
                              void* d_out, int out_size, void* d_ws, size_t ws_size,
                              hipStream_t stream) {
    const float* x = (const float*)d_in[0];
    char* w = (char*)d_ws;

    // workspace layout (bytes), total ~6.38 MB
    unsigned long long* cand     = (unsigned long long*)(w + 0);        // 16*4096*8 = 524288
    unsigned long long* mask     = (unsigned long long*)(w + 524288);   // 16*1024*16*8 = 2097152
    unsigned long long* keepbits = (unsigned long long*)(w + 2621440);  // 16*16*8 = 2048
    unsigned*           hist     = (unsigned*)(w + 2623488);            // 16*16384*4 = 1048576
    unsigned*           k32      = (unsigned*)(w + 3672064);            // 403200*4 = 1612800
    float4*             topbox   = (float4*)(w + 5284864);              // 16*1024*16 = 262144
    float4*             topoff   = (float4*)(w + 5547008);              // 262144
    float*              topconf  = (float*)(w + 5809152);               // 65536
    float*              topcls   = (float*)(w + 5874688);               // 65536
    unsigned*           cutoff   = (unsigned*)(w + 5940224);            // 64
    unsigned*           ncand    = (unsigned*)(w + 5940288);            // 64
    unsigned char*      cls8     = (unsigned char*)(w + 5940352);       // 403200
    unsigned short*     summ     = (unsigned short*)(w + 6343552);      // 16*1024*2 = 32768
    if (ws_size < 6376320) return;  // insufficient scratch -> deterministic failure

    hipMemsetAsync(hist, 0, (size_t)BATCH * HIST_SIZE * sizeof(unsigned), stream);
    hipMemsetAsync(ncand, 0, (size_t)BATCH * sizeof(unsigned), stream);

    score_kernel<<<(BATCH * NBOX) / 256, 256, 0, stream>>>(x, k32, cls8, hist);
    select_cutoff<<<BATCH, 256, 0, stream>>>(hist, cutoff);
    compact_kernel<<<dim3((NBOX + 255) / 256, BATCH), 256, 0, stream>>>(k32, cutoff, ncand, cand);
    sort_gather<<<BATCH, 1024, 0, stream>>>(cand, ncand, x, cls8, topbox, topoff, topconf, topcls);
    iou_mask<<<BATCH * 64, 256, 0, stream>>>(topoff, mask, summ);
    nms_reduce<<<BATCH, 64, 0, stream>>>(mask, summ, topconf, keepbits);

    float* dets = (float*)d_out;
    float* vmask = dets + (size_t)BATCH * MAXDET * 6;
    finalize_kernel<<<BATCH, 1024, 0, stream>>>(keepbits, topbox, topconf, topcls, dets, vmask);
}

// Round 6
// 195.937 us; speedup vs baseline: 2.6407x; 1.3331x over previous
//
#include <hip/hip_runtime.h>
#include <cstdint>
#include <cstddef>

// ---------------- problem constants ----------------
#define BATCH 16
#define NBOX 25200
#define NCH 85          // 4 box + 1 obj + 80 cls
#define KPRE 1024
#define MAXDET 1000
#define NCAND_MAX 4096
#define HIST_SIZE 16384 // histogram over (key >> 18)
#define NCHUNK 99       // ceil(NBOX / 256)

__device__ __forceinline__ unsigned key_of(float s) {
    // monotone map: larger score -> SMALLER key (ascending sort = descending score)
    unsigned u = __float_as_uint(s);
    unsigned m = (u & 0x80000000u) ? ~u : (u | 0x80000000u);
    return ~m;
}

// ---------------- kernel 1: per-box score/argmax, key + histogram ----------------
// 4 lanes per box, 20 classes each, direct global loads (no LDS, no barriers).
__global__ __launch_bounds__(256) void score_kernel(const float* __restrict__ x,
                                                    unsigned* __restrict__ k32,
                                                    unsigned char* __restrict__ cls8,
                                                    unsigned* __restrict__ hist) {
    int gid = blockIdx.x * 256 + threadIdx.x;
    int box = gid >> 2;                       // one box per 4 lanes
    int q = gid & 3;
    size_t base = (size_t)box * NCH;

    float obj = x[base + 4];                  // 4 lanes broadcast-load same addr
    int cbase = 5 + q * 20;
    float v = -1e30f; int c = 0;
    #pragma unroll
    for (int j = 0; j < 20; j++) {            // 20 independent loads in flight
        float s = x[base + cbase + j] * obj;
        if (s > v) { v = s; c = q * 20 + j; } // strict > keeps first occurrence in segment
    }
    // combine the 4 segments; tie -> lowest class index (first occurrence)
    #pragma unroll
    for (int off = 1; off <= 2; off <<= 1) {
        float ov = __shfl_xor(v, off);
        int   oc = __shfl_xor(c, off);
        if (ov > v || (ov == v && oc < c)) { v = ov; c = oc; }
    }

    if (q == 0) {
        bool validb = (obj > 0.25f) && (v > 0.25f);
        float score = validb ? v : -1.0f;
        unsigned k = key_of(score);
        k32[box] = k;
        cls8[box] = (unsigned char)c;
        if (validb) {                          // invalid boxes never join the top-k race
            int b = box / NBOX;
            atomicAdd(&hist[b * HIST_SIZE + (k >> 18)], 1u);  // commutative -> deterministic
        }
    }
}

// ---------------- kernel 2: find histogram cutoff prefix covering rank KPRE ----------------
__global__ __launch_bounds__(256) void select_cutoff(const unsigned* __restrict__ hist,
                                                     unsigned* __restrict__ cutoff) {
    int b = blockIdx.x, t = threadIdx.x;
    __shared__ unsigned part[256];
    const unsigned* h = hist + (size_t)b * HIST_SIZE;
    unsigned s = 0;
    for (int j = 0; j < HIST_SIZE / 256; j++) s += h[t * (HIST_SIZE / 256) + j];
    part[t] = s;
    __syncthreads();
    if (t == 0) {
        unsigned cum = 0;
        int chunk = 0;
        for (; chunk < 256; chunk++) {
            if (cum + part[chunk] >= KPRE) break;
            cum += part[chunk];
        }
        unsigned P = HIST_SIZE - 1;             // fewer than KPRE valid -> take all valid
        if (chunk < 256) {
            int base = chunk * (HIST_SIZE / 256);
            for (int j = 0; j < HIST_SIZE / 256; j++) {
                cum += h[base + j];
                if (cum >= KPRE) { P = base + j; break; }
            }
        }
        cutoff[b] = P;
    }
}

// ---------------- kernels 3a/3b/3c: DETERMINISTIC candidate compaction ----------------
// No order-dependent atomics anywhere: count -> exclusive scan -> ordered place.
__device__ __forceinline__ bool cand_pass(const unsigned* k32, const unsigned* cutoff,
                                          int b, int i, unsigned& k) {
    if (i >= NBOX) return false;
    k = k32[(size_t)b * NBOX + i];
    return ((int)k >= 0) && ((k >> 18) <= cutoff[b]);  // sign bit set = invalid (-1 score)
}

__global__ __launch_bounds__(256) void count_kernel(const unsigned* __restrict__ k32,
                                                    const unsigned* __restrict__ cutoff,
                                                    unsigned* __restrict__ chunkCnt) {
    int b = blockIdx.y, chunk = blockIdx.x;
    int i = chunk * 256 + threadIdx.x;
    unsigned k;
    bool pass = cand_pass(k32, cutoff, b, i, k);
    unsigned long long m = __ballot(pass);
    __shared__ unsigned wc[4];
    int lane = threadIdx.x & 63, wid = threadIdx.x >> 6;
    if (lane == 0) wc[wid] = (unsigned)__popcll(m);
    __syncthreads();
    if (threadIdx.x == 0) chunkCnt[b * NCHUNK + chunk] = wc[0] + wc[1] + wc[2] + wc[3];
}

__global__ __launch_bounds__(64) void scan_kernel(unsigned* __restrict__ chunkCnt,
                                                  unsigned* __restrict__ ncand) {
    int b = blockIdx.x;
    if (threadIdx.x == 0) {
        unsigned acc = 0;
        for (int c = 0; c < NCHUNK; c++) {
            unsigned v = chunkCnt[b * NCHUNK + c];
            chunkCnt[b * NCHUNK + c] = acc;     // exclusive offsets in-place
            acc += v;
        }
        ncand[b] = acc;
    }
}

__global__ __launch_bounds__(256) void place_kernel(const unsigned* __restrict__ k32,
                                                    const unsigned* __restrict__ cutoff,
                                                    const unsigned* __restrict__ chunkCnt,
                                                    unsigned long long* __restrict__ cand) {
    int b = blockIdx.y, chunk = blockIdx.x;
    int i = chunk * 256 + threadIdx.x;
    unsigned k = 0;
    bool pass = cand_pass(k32, cutoff, b, i, k);
    unsigned long long m = __ballot(pass);
    __shared__ unsigned wc[4];
    int lane = threadIdx.x & 63, wid = threadIdx.x >> 6;
    if (lane == 0) wc[wid] = (unsigned)__popcll(m);
    __syncthreads();
    unsigned base = chunkCnt[b * NCHUNK + chunk];
    base += (wid > 0 ? wc[0] : 0u) + (wid > 1 ? wc[1] : 0u) + (wid > 2 ? wc[2] : 0u);
    unsigned rank = base + (unsigned)__popcll(lane ? (m & ((~0ull) >> (64 - lane))) : 0ull);
    if (pass && rank < NCAND_MAX)
        cand[(size_t)b * NCAND_MAX + rank] = ((unsigned long long)k << 32) | (unsigned)i;
}

// ---------------- kernel 4: bitonic sort candidates, gather top-1024 ----------------
__global__ __launch_bounds__(1024) void sort_gather(const unsigned long long* __restrict__ cand,
                                                    const unsigned* __restrict__ ncand,
                                                    const float* __restrict__ x,
                                                    const unsigned char* __restrict__ cls8,
                                                    float4* __restrict__ topbox,
                                                    float4* __restrict__ topoff,
                                                    float* __restrict__ topconf,
                                                    float* __restrict__ topcls) {
#pragma clang fp contract(off)
    __shared__ unsigned long long keys[NCAND_MAX];
    int b = blockIdx.x, t = threadIdx.x;
    int n = (int)ncand[b];
    if (n > NCAND_MAX) n = NCAND_MAX;
    for (int q = 0; q < 4; q++) {
        int s = t + q * 1024;
        keys[s] = (s < n) ? cand[(size_t)b * NCAND_MAX + s] : ~0ull;
    }
    __syncthreads();
    // ascending bitonic sort: key ascending = score descending, ties by ascending idx
    for (int k = 2; k <= NCAND_MAX; k <<= 1) {
        for (int j = k >> 1; j > 0; j >>= 1) {
            for (int q = 0; q < 4; q++) {
                int i = t + q * 1024;
                int ixj = i ^ j;
                if (ixj > i) {
                    unsigned long long a = keys[i], bb = keys[ixj];
                    bool up = ((i & k) == 0);
                    if ((a > bb) == up) { keys[i] = bb; keys[ixj] = a; }
                }
            }
            __syncthreads();
        }
    }
    // gather rank t (t in [0,1024))
    float conf; float4 box; float clsf;
    if (t < n) {
        unsigned long long key = keys[t];
        unsigned kk = (unsigned)(key >> 32);
        unsigned idx = (unsigned)(key & 0xFFFFFFFFu);
        unsigned m = ~kk;
        unsigned bits = (m & 0x80000000u) ? (m & 0x7FFFFFFFu) : ~m;
        conf = __uint_as_float(bits);           // exact original score
        size_t base = ((size_t)b * NBOX + idx) * NCH;
        float cx = x[base + 0], cy = x[base + 1], w = x[base + 2], h = x[base + 3];
        box = make_float4(cx - w * 0.5f, cy - h * 0.5f, cx + w * 0.5f, cy + h * 0.5f);
        clsf = (float)cls8[(size_t)b * NBOX + idx];
    } else {
        conf = -1.0f; box = make_float4(0.f, 0.f, 0.f, 0.f); clsf = 0.f;
    }
    int o = (b << 10) + t;
    topconf[o] = conf;
    topcls[o] = clsf;
    topbox[o] = box;
    float off = clsf * 4096.0f;
    topoff[o] = make_float4(box.x + off, box.y + off, box.z + off, box.w + off);
}

// ---------------- kernel 5: pairwise IoU suppression bitmask + per-row summary ----------------
__global__ __launch_bounds__(256) void iou_mask(const float4* __restrict__ topoff,
                                                unsigned long long* __restrict__ mask,
                                                unsigned short* __restrict__ summ) {
#pragma clang fp contract(off)
    __shared__ float4 soff[KPRE];
    int b = blockIdx.x >> 6;
    int blk = blockIdx.x & 63;
    int t = threadIdx.x;
    for (int q = 0; q < 4; q++) {
        int s = t + q * 256;
        soff[s] = topoff[(b << 10) + s];
    }
    __syncthreads();
    int i = (blk << 4) + (t >> 4);
    int w = t & 15;
    float4 a = soff[i];
    float area_a = (a.z - a.x) * (a.w - a.y);
    unsigned long long bits = 0;
    int jbase = w << 6;
    for (int jj = 0; jj < 64; jj++) {
        int j = jbase + jj;
        float4 bb = soff[j];
        float area_b = (bb.z - bb.x) * (bb.w - bb.y);
        float ltx = fmaxf(a.x, bb.x), lty = fmaxf(a.y, bb.y);
        float rbx = fminf(a.z, bb.z), rby = fminf(a.w, bb.w);
        float wx = fmaxf(rbx - ltx, 0.0f), wy = fmaxf(rby - lty, 0.0f);
        float inter = wx * wy;
        float iou = inter / (area_a + area_b - inter + 1e-7f);
        if (j > i && iou > 0.45f) bits |= (1ull << jj);
    }
    mask[((size_t)((b << 10) + i) << 4) + w] = bits;
    // per-row 16-bit summary via wave ballot: lane l = (row quarter q=l>>4, word l&15)
    unsigned long long bal = __ballot(bits != 0ull);
    if (w == 0) {
        int l = t & 63;
        summ[(b << 10) + i] = (unsigned short)((bal >> ((l >> 4) << 4)) & 0xFFFFull);
    }
}

// ---------------- kernel 6: greedy suppression, sparsity-driven (1 wave / batch) ----------------
__global__ __launch_bounds__(64) void nms_reduce(const unsigned long long* __restrict__ mask,
                                                 const unsigned short* __restrict__ summ,
                                                 const float* __restrict__ topconf,
                                                 unsigned long long* __restrict__ keepbits) {
    int b = blockIdx.x, lane = threadIdx.x;
    const unsigned long long* mrow = mask + ((size_t)b << 14);   // 1024 rows x 16 words

    unsigned long long keep0[16];
    #pragma unroll
    for (int c = 0; c < 16; c++) {
        float cf = topconf[(b << 10) + (c << 6) + lane];
        keep0[c] = __ballot(cf > 0.0f);
    }
    unsigned nz[16];
    #pragma unroll
    for (int t = 0; t < 16; t++)
        nz[t] = (unsigned)summ[(b << 10) + (t << 6) + lane];
    unsigned long long diag[16];
    #pragma unroll
    for (int t = 0; t < 16; t++)
        diag[t] = mrow[((size_t)((t << 6) + lane) << 4) + t];

    unsigned long long remv[16];
    #pragma unroll
    for (int t = 0; t < 16; t++) remv[t] = 0;

    #pragma unroll
    for (int t = 0; t < 16; t++) {
        unsigned long long live = keep0[t] & ~remv[t];
        unsigned long long kept = live;
        unsigned long long pend = live & __ballot((nz[t] >> t) & 1u);
        while (pend) {
            int j = (int)__ffsll(pend) - 1;
            pend &= pend - 1;
            if ((kept >> j) & 1ull) {
                unsigned long long dj = __shfl(diag[t], j);  // bits all > j (upper-tri)
                kept &= ~dj;
                pend &= ~dj;
            }
        }
        if (lane == 0) keepbits[b * 16 + t] = kept;

        #pragma unroll
        for (int w = 0; w < 16; w++) {
            if (w > t) {
                unsigned long long wm = kept & __ballot((nz[t] >> w) & 1u);
                while (wm) {
                    int j = (int)__ffsll(wm) - 1;
                    wm &= wm - 1;
                    remv[w] |= mrow[((size_t)((t << 6) + j) << 4) + w]; // broadcast, L1-warm
                }
            }
        }
    }
}

// ---------------- kernel 7: ordered compaction of kept entries -> dets + vmask ----------------
__global__ __launch_bounds__(1024) void finalize_kernel(const unsigned long long* __restrict__ keepbits,
                                                        const float4* __restrict__ topbox,
                                                        const float* __restrict__ topconf,
                                                        const float* __restrict__ topcls,
                                                        float* __restrict__ dets,
                                                        float* __restrict__ vmask) {
    int b = blockIdx.x, r = threadIdx.x;
    int w = r >> 6, l = r & 63;
    unsigned long long word = keepbits[b * 16 + w];
    int keep = (int)((word >> l) & 1ull);
    __shared__ int wsum[16];
    if (l == 0) wsum[w] = __popcll(word);
    __syncthreads();
    int base = 0, total = 0;
    for (int q = 0; q < 16; q++) {
        int c = wsum[q];
        total += c;
        if (q < w) base += c;
    }
    int rank = base + __popcll((l == 0) ? 0ull : (word & ((~0ull) >> (64 - l))));
    float* drow = dets + (size_t)b * (MAXDET * 6);
    float* vm = vmask + (size_t)b * MAXDET;
    if (r < MAXDET && r >= total) {
#pragma unroll
        for (int cc = 0; cc < 6; cc++) drow[r * 6 + cc] = 0.0f;
        vm[r] = 0.0f;
    }
    if (keep && rank < MAXDET) {
        int o = (b << 10) + r;
        float4 bx = topbox[o];
        drow[rank * 6 + 0] = bx.x;
        drow[rank * 6 + 1] = bx.y;
        drow[rank * 6 + 2] = bx.z;
        drow[rank * 6 + 3] = bx.w;
        drow[rank * 6 + 4] = topconf[o];
        drow[rank * 6 + 5] = topcls[o];
        vm[rank] = 1.0f;
    }
}

// ---------------- launcher ----------------
extern "C" void kernel_launch(void* const* d_in, const int* in_sizes, int n_in,
                              void* d_out, int out_size, void* d_ws, size_t ws_size,
                              hipStream_t stream) {
    const float* x = (const float*)d_in[0];
    char* w = (char*)d_ws;

    // workspace layout (bytes), total ~6.39 MB
    unsigned long long* cand     = (unsigned long long*)(w + 0);        // 16*4096*8 = 524288
    unsigned long long* mask     = (unsigned long long*)(w + 524288);   // 16*1024*16*8 = 2097152
    unsigned long long* keepbits = (unsigned long long*)(w + 2621440);  // 16*16*8 = 2048
    unsigned*           hist     = (unsigned*)(w + 2623488);            // 16*16384*4 = 1048576
    unsigned*           k32      = (unsigned*)(w + 3672064);            // 403200*4 = 1612800
    float4*             topbox   = (float4*)(w + 5284864);              // 16*1024*16 = 262144
    float4*             topoff   = (float4*)(w + 5547008);              // 262144
    float*              topconf  = (float*)(w + 5809152);               // 65536
    float*              topcls   = (float*)(w + 5874688);               // 65536
    unsigned*           cutoff   = (unsigned*)(w + 5940224);            // 64
    unsigned*           ncand    = (unsigned*)(w + 5940288);            // 64
    unsigned char*      cls8     = (unsigned char*)(w + 5940352);       // 403200
    unsigned short*     summ     = (unsigned short*)(w + 6343552);      // 16*1024*2 = 32768
    unsigned*           chunkCnt = (unsigned*)(w + 6376320);            // 16*99*4 = 6336
    if (ws_size < 6382656) return;  // insufficient scratch -> deterministic failure

    hipMemsetAsync(hist, 0, (size_t)BATCH * HIST_SIZE * sizeof(unsigned), stream);

    score_kernel<<<(BATCH * NBOX * 4) / 256, 256, 0, stream>>>(x, k32, cls8, hist);
    select_cutoff<<<BATCH, 256, 0, stream>>>(hist, cutoff);
    count_kernel<<<dim3(NCHUNK, BATCH), 256, 0, stream>>>(k32, cutoff, chunkCnt);
    scan_kernel<<<BATCH, 64, 0, stream>>>(chunkCnt, ncand);
    place_kernel<<<dim3(NCHUNK, BATCH), 256, 0, stream>>>(k32, cutoff, chunkCnt, cand);
    sort_gather<<<BATCH, 1024, 0, stream>>>(cand, ncand, x, cls8, topbox, topoff, topconf, topcls);
    iou_mask<<<BATCH * 64, 256, 0, stream>>>(topoff, mask, summ);
    nms_reduce<<<BATCH, 64, 0, stream>>>(mask, summ, topconf, keepbits);

    float* dets = (float*)d_out;
    float* vmask = dets + (size_t)BATCH * MAXDET * 6;
    finalize_kernel<<<BATCH, 1024, 0, stream>>>(keepbits, topbox, topconf, topcls, dets, vmask);
}

// Round 7
// 178.809 us; speedup vs baseline: 2.8937x; 1.0958x over previous
//
#include <hip/hip_runtime.h>
#include <cstdint>
#include <cstddef>

// ---------------- problem constants ----------------
#define BATCH 16
#define NBOX 25200
#define NCH 85          // 4 box + 1 obj + 80 cls
#define KPRE 1024
#define MAXDET 1000
#define NCAND_MAX 4096
#define HIST_SIZE 16384 // histogram over (key >> 18)
#define NCHUNK 99       // ceil(NBOX / 256)

__device__ __forceinline__ unsigned key_of(float s) {
    // monotone map: larger score -> SMALLER key (ascending sort = descending score)
    unsigned u = __float_as_uint(s);
    unsigned m = (u & 0x80000000u) ? ~u : (u | 0x80000000u);
    return ~m;
}

// ---------------- kernel 1: per-box score/argmax, key + histogram ----------------
// 2 lanes per box, 40 classes each as 10 independent float4 loads held in registers
// (one waitcnt, ~176B in flight per lane). CDNA global loads support dword alignment.
__global__ __launch_bounds__(256) void score_kernel(const float* __restrict__ x,
                                                    unsigned* __restrict__ k32,
                                                    unsigned char* __restrict__ cls8,
                                                    unsigned* __restrict__ hist) {
    int gid = blockIdx.x * 256 + threadIdx.x;
    int box = gid >> 1;                       // one box per 2 lanes
    int q = gid & 1;
    size_t base = (size_t)box * NCH;

    float obj = x[base + 4];
    const float4* p = (const float4*)(x + base + 5 + q * 40);
    float4 r[10];
    #pragma unroll
    for (int j = 0; j < 10; j++) r[j] = p[j];  // all independent, issue together

    float v = -1e30f; int c = 0;
    #pragma unroll
    for (int j = 0; j < 10; j++) {             // strict > keeps first occurrence
        float s0 = r[j].x * obj; if (s0 > v) { v = s0; c = q * 40 + j * 4 + 0; }
        float s1 = r[j].y * obj; if (s1 > v) { v = s1; c = q * 40 + j * 4 + 1; }
        float s2 = r[j].z * obj; if (s2 > v) { v = s2; c = q * 40 + j * 4 + 2; }
        float s3 = r[j].w * obj; if (s3 > v) { v = s3; c = q * 40 + j * 4 + 3; }
    }
    // combine the 2 halves; tie -> lowest class index (first occurrence)
    float ov = __shfl_xor(v, 1);
    int   oc = __shfl_xor(c, 1);
    if (ov > v || (ov == v && oc < c)) { v = ov; c = oc; }

    if (q == 0) {
        bool validb = (obj > 0.25f) && (v > 0.25f);
        float score = validb ? v : -1.0f;
        unsigned k = key_of(score);
        k32[box] = k;
        cls8[box] = (unsigned char)c;
        if (validb) {                          // invalid boxes never join the top-k race
            int b = box / NBOX;
            atomicAdd(&hist[b * HIST_SIZE + (k >> 18)], 1u);  // commutative -> deterministic
        }
    }
}

// ---------------- kernel 2: find histogram cutoff prefix covering rank KPRE ----------------
__global__ __launch_bounds__(256) void select_cutoff(const unsigned* __restrict__ hist,
                                                     unsigned* __restrict__ cutoff) {
    int b = blockIdx.x, t = threadIdx.x;
    __shared__ unsigned part[256];
    const unsigned* h = hist + (size_t)b * HIST_SIZE;
    unsigned s = 0;
    for (int j = 0; j < HIST_SIZE / 256; j++) s += h[t * (HIST_SIZE / 256) + j];
    part[t] = s;
    __syncthreads();
    if (t == 0) {
        unsigned cum = 0;
        int chunk = 0;
        for (; chunk < 256; chunk++) {
            if (cum + part[chunk] >= KPRE) break;
            cum += part[chunk];
        }
        unsigned P = HIST_SIZE - 1;             // fewer than KPRE valid -> take all valid
        if (chunk < 256) {
            int base = chunk * (HIST_SIZE / 256);
            for (int j = 0; j < HIST_SIZE / 256; j++) {
                cum += h[base + j];
                if (cum >= KPRE) { P = base + j; break; }
            }
        }
        cutoff[b] = P;
    }
}

// ---------------- kernels 3a/3b/3c: DETERMINISTIC candidate compaction ----------------
__device__ __forceinline__ bool cand_pass(const unsigned* k32, const unsigned* cutoff,
                                          int b, int i, unsigned& k) {
    if (i >= NBOX) return false;
    k = k32[(size_t)b * NBOX + i];
    return ((int)k >= 0) && ((k >> 18) <= cutoff[b]);  // sign bit set = invalid (-1 score)
}

__global__ __launch_bounds__(256) void count_kernel(const unsigned* __restrict__ k32,
                                                    const unsigned* __restrict__ cutoff,
                                                    unsigned* __restrict__ chunkCnt) {
    int b = blockIdx.y, chunk = blockIdx.x;
    int i = chunk * 256 + threadIdx.x;
    unsigned k;
    bool pass = cand_pass(k32, cutoff, b, i, k);
    unsigned long long m = __ballot(pass);
    __shared__ unsigned wc[4];
    int lane = threadIdx.x & 63, wid = threadIdx.x >> 6;
    if (lane == 0) wc[wid] = (unsigned)__popcll(m);
    __syncthreads();
    if (threadIdx.x == 0) chunkCnt[b * NCHUNK + chunk] = wc[0] + wc[1] + wc[2] + wc[3];
}

// parallel per-batch exclusive scan of 99 chunk counts (Hillis-Steele in LDS)
__global__ __launch_bounds__(128) void scan_kernel(unsigned* __restrict__ chunkCnt,
                                                   unsigned* __restrict__ ncand) {
    int b = blockIdx.x, t = threadIdx.x;
    __shared__ unsigned s[128];
    unsigned v = (t < NCHUNK) ? chunkCnt[b * NCHUNK + t] : 0u;
    s[t] = v;
    __syncthreads();
    #pragma unroll
    for (int off = 1; off < 128; off <<= 1) {
        unsigned u = (t >= off) ? s[t - off] : 0u;
        __syncthreads();
        s[t] += u;
        __syncthreads();
    }
    if (t < NCHUNK) chunkCnt[b * NCHUNK + t] = s[t] - v;   // exclusive
    if (t == NCHUNK - 1) ncand[b] = s[t];
}

__global__ __launch_bounds__(256) void place_kernel(const unsigned* __restrict__ k32,
                                                    const unsigned* __restrict__ cutoff,
                                                    const unsigned* __restrict__ chunkCnt,
                                                    unsigned long long* __restrict__ cand) {
    int b = blockIdx.y, chunk = blockIdx.x;
    int i = chunk * 256 + threadIdx.x;
    unsigned k = 0;
    bool pass = cand_pass(k32, cutoff, b, i, k);
    unsigned long long m = __ballot(pass);
    __shared__ unsigned wc[4];
    int lane = threadIdx.x & 63, wid = threadIdx.x >> 6;
    if (lane == 0) wc[wid] = (unsigned)__popcll(m);
    __syncthreads();
    unsigned base = chunkCnt[b * NCHUNK + chunk];
    base += (wid > 0 ? wc[0] : 0u) + (wid > 1 ? wc[1] : 0u) + (wid > 2 ? wc[2] : 0u);
    unsigned rank = base + (unsigned)__popcll(lane ? (m & ((~0ull) >> (64 - lane))) : 0ull);
    if (pass && rank < NCAND_MAX)
        cand[(size_t)b * NCAND_MAX + rank] = ((unsigned long long)k << 32) | (unsigned)i;
}

// ---------------- kernel 4: bitonic sort candidates (dynamic size), gather top-1024 ----------------
__global__ __launch_bounds__(1024) void sort_gather(const unsigned long long* __restrict__ cand,
                                                    const unsigned* __restrict__ ncand,
                                                    const float* __restrict__ x,
                                                    const unsigned char* __restrict__ cls8,
                                                    float4* __restrict__ topbox,
                                                    float4* __restrict__ topoff,
                                                    float* __restrict__ topconf,
                                                    float* __restrict__ topcls) {
#pragma clang fp contract(off)
    __shared__ unsigned long long keys[NCAND_MAX];
    int b = blockIdx.x, t = threadIdx.x;
    int n = (int)ncand[b];
    if (n > NCAND_MAX) n = NCAND_MAX;
    int m = KPRE;                               // smallest pow2 >= max(n, 1024)
    while (m < n) m <<= 1;
    int nq = m >> 10;                           // elements per thread
    for (int q = 0; q < nq; q++) {
        int s = t + (q << 10);
        keys[s] = (s < n) ? cand[(size_t)b * NCAND_MAX + s] : ~0ull;
    }
    __syncthreads();
    // ascending bitonic sort: key ascending = score descending, ties by ascending idx
    for (int k = 2; k <= m; k <<= 1) {
        for (int j = k >> 1; j > 0; j >>= 1) {
            for (int q = 0; q < nq; q++) {
                int i = t + (q << 10);
                int ixj = i ^ j;
                if (ixj > i) {
                    unsigned long long a = keys[i], bb = keys[ixj];
                    bool up = ((i & k) == 0);
                    if ((a > bb) == up) { keys[i] = bb; keys[ixj] = a; }
                }
            }
            __syncthreads();
        }
    }
    // gather rank t (t in [0,1024))
    float conf; float4 box; float clsf;
    if (t < n) {
        unsigned long long key = keys[t];
        unsigned kk = (unsigned)(key >> 32);
        unsigned idx = (unsigned)(key & 0xFFFFFFFFu);
        unsigned mm = ~kk;
        unsigned bits = (mm & 0x80000000u) ? (mm & 0x7FFFFFFFu) : ~mm;
        conf = __uint_as_float(bits);           // exact original score
        size_t base = ((size_t)b * NBOX + idx) * NCH;
        float cx = x[base + 0], cy = x[base + 1], w = x[base + 2], h = x[base + 3];
        box = make_float4(cx - w * 0.5f, cy - h * 0.5f, cx + w * 0.5f, cy + h * 0.5f);
        clsf = (float)cls8[(size_t)b * NBOX + idx];
    } else {
        conf = -1.0f; box = make_float4(0.f, 0.f, 0.f, 0.f); clsf = 0.f;
    }
    int o = (b << 10) + t;
    topconf[o] = conf;
    topcls[o] = clsf;
    topbox[o] = box;
    float off = clsf * 4096.0f;
    topoff[o] = make_float4(box.x + off, box.y + off, box.z + off, box.w + off);
}

// ---------------- kernel 5: pairwise IoU suppression bitmask + per-row summary ----------------
__global__ __launch_bounds__(256) void iou_mask(const float4* __restrict__ topoff,
                                                unsigned long long* __restrict__ mask,
                                                unsigned short* __restrict__ summ) {
#pragma clang fp contract(off)
    __shared__ float4 soff[KPRE];
    int b = blockIdx.x >> 6;
    int blk = blockIdx.x & 63;
    int t = threadIdx.x;
    for (int q = 0; q < 4; q++) {
        int s = t + q * 256;
        soff[s] = topoff[(b << 10) + s];
    }
    __syncthreads();
    int i = (blk << 4) + (t >> 4);
    int w = t & 15;
    unsigned long long bits = 0;
    int jbase = w << 6;
    if (jbase + 63 > i) {                       // lower-triangle words are identically 0
        float4 a = soff[i];
        float area_a = (a.z - a.x) * (a.w - a.y);
        for (int jj = 0; jj < 64; jj++) {
            int j = jbase + jj;
            float4 bb = soff[j];
            float area_b = (bb.z - bb.x) * (bb.w - bb.y);
            float ltx = fmaxf(a.x, bb.x), lty = fmaxf(a.y, bb.y);
            float rbx = fminf(a.z, bb.z), rby = fminf(a.w, bb.w);
            float wx = fmaxf(rbx - ltx, 0.0f), wy = fmaxf(rby - lty, 0.0f);
            float inter = wx * wy;
            float iou = inter / (area_a + area_b - inter + 1e-7f);
            if (j > i && iou > 0.45f) bits |= (1ull << jj);
        }
    }
    mask[((size_t)((b << 10) + i) << 4) + w] = bits;
    // per-row 16-bit summary via wave ballot: lane l = (row quarter q=l>>4, word l&15)
    unsigned long long bal = __ballot(bits != 0ull);
    if (w == 0) {
        int l = t & 63;
        summ[(b << 10) + i] = (unsigned short)((bal >> ((l >> 4) << 4)) & 0xFFFFull);
    }
}

// ---------------- kernel 6: greedy suppression, sparsity-driven (1 wave / batch) ----------------
__global__ __launch_bounds__(64) void nms_reduce(const unsigned long long* __restrict__ mask,
                                                 const unsigned short* __restrict__ summ,
                                                 const float* __restrict__ topconf,
                                                 unsigned long long* __restrict__ keepbits) {
    int b = blockIdx.x, lane = threadIdx.x;
    const unsigned long long* mrow = mask + ((size_t)b << 14);   // 1024 rows x 16 words

    unsigned long long keep0[16];
    #pragma unroll
    for (int c = 0; c < 16; c++) {
        float cf = topconf[(b << 10) + (c << 6) + lane];
        keep0[c] = __ballot(cf > 0.0f);
    }
    unsigned nz[16];
    #pragma unroll
    for (int t = 0; t < 16; t++)
        nz[t] = (unsigned)summ[(b << 10) + (t << 6) + lane];
    unsigned long long diag[16];
    #pragma unroll
    for (int t = 0; t < 16; t++)
        diag[t] = mrow[((size_t)((t << 6) + lane) << 4) + t];

    unsigned long long remv[16];
    #pragma unroll
    for (int t = 0; t < 16; t++) remv[t] = 0;

    #pragma unroll
    for (int t = 0; t < 16; t++) {
        unsigned long long live = keep0[t] & ~remv[t];
        unsigned long long kept = live;
        unsigned long long pend = live & __ballot((nz[t] >> t) & 1u);
        while (pend) {
            int j = (int)__ffsll(pend) - 1;
            pend &= pend - 1;
            if ((kept >> j) & 1ull) {
                unsigned long long dj = __shfl(diag[t], j);  // bits all > j (upper-tri)
                kept &= ~dj;
                pend &= ~dj;
            }
        }
        if (lane == 0) keepbits[b * 16 + t] = kept;

        #pragma unroll
        for (int w = 0; w < 16; w++) {
            if (w > t) {
                unsigned long long wm = kept & __ballot((nz[t] >> w) & 1u);
                while (wm) {
                    int j = (int)__ffsll(wm) - 1;
                    wm &= wm - 1;
                    remv[w] |= mrow[((size_t)((t << 6) + j) << 4) + w]; // broadcast, L1-warm
                }
            }
        }
    }
}

// ---------------- kernel 7: ordered compaction of kept entries -> dets + vmask ----------------
__global__ __launch_bounds__(1024) void finalize_kernel(const unsigned long long* __restrict__ keepbits,
                                                        const float4* __restrict__ topbox,
                                                        const float* __restrict__ topconf,
                                                        const float* __restrict__ topcls,
                                                        float* __restrict__ dets,
                                                        float* __restrict__ vmask) {
    int b = blockIdx.x, r = threadIdx.x;
    int w = r >> 6, l = r & 63;
    unsigned long long word = keepbits[b * 16 + w];
    int keep = (int)((word >> l) & 1ull);
    __shared__ int wsum[16];
    if (l == 0) wsum[w] = __popcll(word);
    __syncthreads();
    int base = 0, total = 0;
    for (int q = 0; q < 16; q++) {
        int c = wsum[q];
        total += c;
        if (q < w) base += c;
    }
    int rank = base + __popcll((l == 0) ? 0ull : (word & ((~0ull) >> (64 - l))));
    float* drow = dets + (size_t)b * (MAXDET * 6);
    float* vm = vmask + (size_t)b * MAXDET;
    if (r < MAXDET && r >= total) {
#pragma unroll
        for (int cc = 0; cc < 6; cc++) drow[r * 6 + cc] = 0.0f;
        vm[r] = 0.0f;
    }
    if (keep && rank < MAXDET) {
        int o = (b << 10) + r;
        float4 bx = topbox[o];
        drow[rank * 6 + 0] = bx.x;
        drow[rank * 6 + 1] = bx.y;
        drow[rank * 6 + 2] = bx.z;
        drow[rank * 6 + 3] = bx.w;
        drow[rank * 6 + 4] = topconf[o];
        drow[rank * 6 + 5] = topcls[o];
        vm[rank] = 1.0f;
    }
}

// ---------------- launcher ----------------
extern "C" void kernel_launch(void* const* d_in, const int* in_sizes, int n_in,
                              void* d_out, int out_size, void* d_ws, size_t ws_size,
                              hipStream_t stream) {
    const float* x = (const float*)d_in[0];
    char* w = (char*)d_ws;

    // workspace layout (bytes), total ~6.39 MB
    unsigned long long* cand     = (unsigned long long*)(w + 0);        // 16*4096*8 = 524288
    unsigned long long* mask     = (unsigned long long*)(w + 524288);   // 16*1024*16*8 = 2097152
    unsigned long long* keepbits = (unsigned long long*)(w + 2621440);  // 16*16*8 = 2048
    unsigned*           hist     = (unsigned*)(w + 2623488);            // 16*16384*4 = 1048576
    unsigned*           k32      = (unsigned*)(w + 3672064);            // 403200*4 = 1612800
    float4*             topbox   = (float4*)(w + 5284864);              // 16*1024*16 = 262144
    float4*             topoff   = (float4*)(w + 5547008);              // 262144
    float*              topconf  = (float*)(w + 5809152);               // 65536
    float*              topcls   = (float*)(w + 5874688);               // 65536
    unsigned*           cutoff   = (unsigned*)(w + 5940224);            // 64
    unsigned*           ncand    = (unsigned*)(w + 5940288);            // 64
    unsigned char*      cls8     = (unsigned char*)(w + 5940352);       // 403200
    unsigned short*     summ     = (unsigned short*)(w + 6343552);      // 16*1024*2 = 32768
    unsigned*           chunkCnt = (unsigned*)(w + 6376320);            // 16*99*4 = 6336
    if (ws_size < 6382656) return;  // insufficient scratch -> deterministic failure

    hipMemsetAsync(hist, 0, (size_t)BATCH * HIST_SIZE * sizeof(unsigned), stream);

    score_kernel<<<(BATCH * NBOX * 2) / 256, 256, 0, stream>>>(x, k32, cls8, hist);
    select_cutoff<<<BATCH, 256, 0, stream>>>(hist, cutoff);
    count_kernel<<<dim3(NCHUNK, BATCH), 256, 0, stream>>>(k32, cutoff, chunkCnt);
    scan_kernel<<<BATCH, 128, 0, stream>>>(chunkCnt, ncand);
    place_kernel<<<dim3(NCHUNK, BATCH), 256, 0, stream>>>(k32, cutoff, chunkCnt, cand);
    sort_gather<<<BATCH, 1024, 0, stream>>>(cand, ncand, x, cls8, topbox, topoff, topconf, topcls);
    iou_mask<<<BATCH * 64, 256, 0, stream>>>(topoff, mask, summ);
    nms_reduce<<<BATCH, 64, 0, stream>>>(mask, summ, topconf, keepbits);

    float* dets = (float*)d_out;
    float* vmask = dets + (size_t)BATCH * MAXDET * 6;
    finalize_kernel<<<BATCH, 1024, 0, stream>>>(keepbits, topbox, topconf, topcls, dets, vmask);
}